// Round 4
// baseline (183.693 us; speedup 1.0000x reference)
//
#include <hip/hip_runtime.h>
#include <math.h>

#define T_  2048
#define C_  1024
#define HD_ 64

typedef __attribute__((ext_vector_type(8))) short bf16x8;   // 8 bf16 = 4 VGPRs
typedef __attribute__((ext_vector_type(4))) float f32x4;    // MFMA C/D

#define MFMA_BF16(A, B, C) __builtin_amdgcn_mfma_f32_16x16x32_bf16(A, B, C, 0, 0, 0)

__device__ __forceinline__ short f2bf(float f) {
    union { float f; unsigned u; } v; v.f = f;
    unsigned r = v.u + 0x7fffu + ((v.u >> 16) & 1u);   // RTNE
    return (short)(r >> 16);
}
__device__ __forceinline__ float bf2f(short s) {
    union { float f; unsigned u; } v;
    v.u = ((unsigned)(unsigned short)s) << 16;
    return v.f;
}

// ---------------------------------------------------------------------------
// K0: W[1024][64] fp32 -> wt[m][pl][64 h][1024 c] bf16 hi/lo (transposed).
// LDS transpose for coalesced bf16x8 stores. grid (16,3) x 256.
// ---------------------------------------------------------------------------
__global__ __launch_bounds__(256) void prep_w_kernel(
    const float* __restrict__ Wq, const float* __restrict__ Wk,
    const float* __restrict__ Wv, short* __restrict__ wt)
{
    __shared__ __align__(16) short hi_l[64 * 72], lo_l[64 * 72];
    const int m = blockIdx.y;
    const float* W = (m == 0) ? Wq : (m == 1) ? Wk : Wv;
    const int t = threadIdx.x;
    const int C0 = blockIdx.x * 64;
    {
        const int c = t >> 2, hq = t & 3;
        const float4* wp = (const float4*)(W + (size_t)(C0 + c) * HD_ + hq * 16);
        #pragma unroll
        for (int u = 0; u < 4; ++u) {
            float4 f = wp[u];
            float vs[4] = {f.x, f.y, f.z, f.w};
            #pragma unroll
            for (int e = 0; e < 4; ++e) {
                int h = hq * 16 + u * 4 + e;
                short hh = f2bf(vs[e]);
                hi_l[h * 72 + c] = hh;
                lo_l[h * 72 + c] = f2bf(vs[e] - bf2f(hh));
            }
        }
    }
    __syncthreads();
    {
        const int h = t >> 2, cc = (t & 3) * 16;
        short* dh = wt + (size_t)(m * 2 + 0) * 65536 + h * 1024 + C0 + cc;
        short* dl = wt + (size_t)(m * 2 + 1) * 65536 + h * 1024 + C0 + cc;
        *(bf16x8*)dh       = *(const bf16x8*)&hi_l[h * 72 + cc];
        *(bf16x8*)(dh + 8) = *(const bf16x8*)&hi_l[h * 72 + cc + 8];
        *(bf16x8*)dl       = *(const bf16x8*)&lo_l[h * 72 + cc];
        *(bf16x8*)(dl + 8) = *(const bf16x8*)&lo_l[h * 72 + cc + 8];
    }
}

// ---------------------------------------------------------------------------
// K1: QKV projection, barrier-free main loop. grid 256 x 512 thr.
// Block = 32 rows. Wave = (kq = k-half of C, colq = 16-h quarter); per wave:
// q,k triple hi/lo MFMA + v single-plane swapped (-> vT). Fragments loaded
// DIRECTLY from global (A/B lane layout = 8 contiguous k at fixed row/col).
// Single barrier: k-split-2 reduction via LDS, then epilogue.
// ---------------------------------------------------------------------------
__global__ __launch_bounds__(512) void qkv_proj_kernel(
    const float* __restrict__ x, const short* __restrict__ wt,
    short* __restrict__ qhp, short* __restrict__ qlp,
    short* __restrict__ khp, short* __restrict__ klp,
    short* __restrict__ vtp)
{
    __shared__ __align__(16) float pbuf[4 * 64 * 28];   // 28 KB

    const int t = threadIdx.x, L = t & 63, wv = t >> 6;
    const int kq = wv & 1, colq = wv >> 1;
    const int R0 = blockIdx.x * 32;
    const int h = colq * 16 + (L & 15);

    f32x4 acc[2][3];
    #pragma unroll
    for (int i = 0; i < 2; ++i)
        #pragma unroll
        for (int j = 0; j < 3; ++j) acc[i][j] = {0.f, 0.f, 0.f, 0.f};

    const int c_base = kq * 512 + (L >> 4) * 8;
    const float* xp0 = x + (size_t)(R0 + (L & 15)) * C_ + c_base;
    const float* xp1 = x + (size_t)(R0 + 16 + (L & 15)) * C_ + c_base;
    const short* wq_h = wt + (size_t)0 * 65536 + h * 1024 + c_base;
    const short* wq_l = wt + (size_t)1 * 65536 + h * 1024 + c_base;
    const short* wk_h = wt + (size_t)2 * 65536 + h * 1024 + c_base;
    const short* wk_l = wt + (size_t)3 * 65536 + h * 1024 + c_base;
    const short* wv_h = wt + (size_t)4 * 65536 + h * 1024 + c_base;

    for (int it = 0; it < 16; ++it) {
        const int c0 = it * 32;
        // x fragments (fp32 -> hi/lo bf16 in-register)
        bf16x8 axh[2], axl[2];
        #pragma unroll
        for (int rt = 0; rt < 2; ++rt) {
            const float* xp = rt ? xp1 : xp0;
            float4 f0 = *(const float4*)(xp + c0);
            float4 f1 = *(const float4*)(xp + c0 + 4);
            float vs[8] = {f0.x, f0.y, f0.z, f0.w, f1.x, f1.y, f1.z, f1.w};
            #pragma unroll
            for (int e = 0; e < 8; ++e) {
                short hh = f2bf(vs[e]);
                axh[rt][e] = hh;
                axl[rt][e] = f2bf(vs[e] - bf2f(hh));
            }
        }
        // W fragments direct from global
        bf16x8 qh_f = *(const bf16x8*)(wq_h + c0);
        bf16x8 ql_f = *(const bf16x8*)(wq_l + c0);
        bf16x8 kh_f = *(const bf16x8*)(wk_h + c0);
        bf16x8 kl_f = *(const bf16x8*)(wk_l + c0);
        bf16x8 vh_f = *(const bf16x8*)(wv_h + c0);
        #pragma unroll
        for (int rt = 0; rt < 2; ++rt) {
            acc[rt][0] = MFMA_BF16(axl[rt], qh_f, acc[rt][0]);
            acc[rt][0] = MFMA_BF16(axh[rt], ql_f, acc[rt][0]);
            acc[rt][0] = MFMA_BF16(axh[rt], qh_f, acc[rt][0]);
            acc[rt][1] = MFMA_BF16(axl[rt], kh_f, acc[rt][1]);
            acc[rt][1] = MFMA_BF16(axh[rt], kl_f, acc[rt][1]);
            acc[rt][1] = MFMA_BF16(axh[rt], kh_f, acc[rt][1]);
            acc[rt][2] = MFMA_BF16(vh_f, axh[rt], acc[rt][2]);   // swapped -> D[h][t]
        }
    }

    // ---- k-split reduce: kq=1 writes partials, kq=0 sums + stores
    if (kq == 1) {
        float* pb = &pbuf[(colq * 64 + L) * 28];
        #pragma unroll
        for (int rt = 0; rt < 2; ++rt)
            #pragma unroll
            for (int j = 0; j < 3; ++j)
                *(f32x4*)&pb[(rt * 3 + j) * 4] = acc[rt][j];
    }
    __syncthreads();
    if (kq == 0) {
        const float* pb = &pbuf[(colq * 64 + L) * 28];
        const int quad = L >> 4;
        #pragma unroll
        for (int rt = 0; rt < 2; ++rt) {
            f32x4 aq = acc[rt][0] + *(const f32x4*)&pb[(rt * 3 + 0) * 4];
            f32x4 ak = acc[rt][1] + *(const f32x4*)&pb[(rt * 3 + 1) * 4];
            f32x4 av = acc[rt][2] + *(const f32x4*)&pb[(rt * 3 + 2) * 4];
            #pragma unroll
            for (int r = 0; r < 4; ++r) {
                int row = R0 + rt * 16 + quad * 4 + r;
                // q (x8 scale folded)
                float vq = aq[r] * 8.f;
                short hq2 = f2bf(vq);
                qhp[(size_t)row * HD_ + h] = hq2;
                qlp[(size_t)row * HD_ + h] = f2bf(vq - bf2f(hq2));
                // k
                float vk = ak[r];
                short hk2 = f2bf(vk);
                khp[(size_t)row * HD_ + h] = hk2;
                klp[(size_t)row * HD_ + h] = f2bf(vk - bf2f(hk2));
                // v transposed: d = colq*16 + quad*4 + r, col = t-index
                int d = colq * 16 + quad * 4 + r;
                int tt = R0 + rt * 16 + (L & 15);
                int bb = tt >> 11, tl = tt & (T_ - 1);
                vtp[(size_t)(bb * 64 + d) * T_ + tl] = f2bf(av[r]);
            }
        }
    }
}

// ---------------------------------------------------------------------------
// K2: full-row softmax stats, zero-LDS sweep. grid 512 x 256 thr.
// Block = 16-row tile; wave = 512-col segment. K fragments direct from
// global; deferred-max over 2 chunks of 16 col-tiles; shfl col-merge; one
// barrier for 4-seg merge. Writes final m and 1/l.
// ---------------------------------------------------------------------------
__global__ __launch_bounds__(256) void stats_kernel(
    const short* __restrict__ qhp, const short* __restrict__ qlp,
    const short* __restrict__ khp, const short* __restrict__ klp,
    float* __restrict__ msp, float* __restrict__ ilp)
{
    __shared__ float smem[4][16][2];

    const int t = threadIdx.x, L = t & 63, wv = t >> 6;
    const int R0 = blockIdx.x * 16;           // global row (0..8191)
    const int b = R0 >> 11;
    const int CB = (b << 11) + wv * 512;      // global col base for this seg

    bf16x8 qfh[2], qfl[2];
    {
        int row = R0 + (L & 15);
        #pragma unroll
        for (int dc = 0; dc < 2; ++dc) {
            size_t off = (size_t)row * HD_ + dc * 32 + (L >> 4) * 8;
            qfh[dc] = *(const bf16x8*)(qhp + off);
            qfl[dc] = *(const bf16x8*)(qlp + off);
        }
    }

    float M[4], S[4];
    #pragma unroll
    for (int r = 0; r < 4; ++r) { M[r] = -1e30f; S[r] = 0.f; }

    for (int chunk = 0; chunk < 2; ++chunk) {
        f32x4 s[16];
        #pragma unroll
        for (int ct = 0; ct < 16; ++ct) {
            int col = CB + (chunk * 16 + ct) * 16 + (L & 15);
            const short* kb  = khp + (size_t)col * HD_ + (L >> 4) * 8;
            const short* kb2 = klp + (size_t)col * HD_ + (L >> 4) * 8;
            bf16x8 kf0 = *(const bf16x8*)kb;
            bf16x8 kf1 = *(const bf16x8*)(kb + 32);
            bf16x8 kl0 = *(const bf16x8*)kb2;
            bf16x8 kl1 = *(const bf16x8*)(kb2 + 32);
            f32x4 a = {0.f, 0.f, 0.f, 0.f};
            a = MFMA_BF16(qfl[0], kf0, a);
            a = MFMA_BF16(qfh[0], kl0, a);
            a = MFMA_BF16(qfh[0], kf0, a);
            a = MFMA_BF16(qfl[1], kf1, a);
            a = MFMA_BF16(qfh[1], kl1, a);
            a = MFMA_BF16(qfh[1], kf1, a);
            s[ct] = a;
        }
        #pragma unroll
        for (int r = 0; r < 4; ++r) {
            float mc = s[0][r];
            #pragma unroll
            for (int ct = 1; ct < 16; ++ct) mc = fmaxf(mc, s[ct][r]);
            float lc = 0.f;
            #pragma unroll
            for (int ct = 0; ct < 16; ++ct) lc += __expf(s[ct][r] - mc);
            float mn = fmaxf(M[r], mc);
            S[r] = S[r] * __expf(M[r] - mn) + lc * __expf(mc - mn);
            M[r] = mn;
        }
    }
    // merge the 16 col-lanes
    #pragma unroll
    for (int off = 1; off < 16; off <<= 1)
        #pragma unroll
        for (int r = 0; r < 4; ++r) {
            float mo = __shfl_xor(M[r], off, 64);
            float lo = __shfl_xor(S[r], off, 64);
            float mn = fmaxf(M[r], mo);
            S[r] = S[r] * __expf(M[r] - mn) + lo * __expf(mo - mn);
            M[r] = mn;
        }
    if ((L & 15) == 0) {
        #pragma unroll
        for (int r = 0; r < 4; ++r) {
            smem[wv][(L >> 4) * 4 + r][0] = M[r];
            smem[wv][(L >> 4) * 4 + r][1] = S[r];
        }
    }
    __syncthreads();
    if (t < 16) {
        float Mm = smem[0][t][0], Ss = smem[0][t][1];
        #pragma unroll
        for (int w = 1; w < 4; ++w) {
            float mo = smem[w][t][0], lo = smem[w][t][1];
            float mn = fmaxf(Mm, mo);
            Ss = Ss * __expf(Mm - mn) + lo * __expf(mo - mn);
            Mm = mn;
        }
        msp[R0 + t] = Mm;
        ilp[R0 + t] = 1.f / Ss;
    }
}

// ---------------------------------------------------------------------------
// K3: causal second softmax + PV. grid 256 x 512 thr, paired tiles p,127-p.
// K/V fragments direct from global; es fp32 stride-132 (bank-clean);
// 2 barriers/iter, no staged loads.
// ---------------------------------------------------------------------------
__global__ __launch_bounds__(512) void pv_kernel(
    const short* __restrict__ qhp, const short* __restrict__ qlp,
    const short* __restrict__ khp, const short* __restrict__ klp,
    const short* __restrict__ vtp, const float* __restrict__ msp,
    const float* __restrict__ ilp, float* __restrict__ out)
{
    __shared__ __align__(16) float es[32 * 132];    // 16.9 KB
    __shared__ float red[8 * 32];
    __shared__ float dinv[32];
    __shared__ float obuf[4 * 64 * 8];              // 8 KB

    const int t = threadIdx.x, L = t & 63, wv = t >> 6;
    const int b = blockIdx.x >> 6, p = blockIdx.x & 63;
    const int IA = p * 16, IB = (127 - p) * 16;

    // q fragments
    bf16x8 qfh[2][2], qfl[2][2];
    #pragma unroll
    for (int rt = 0; rt < 2; ++rt) {
        int row = (rt ? IB : IA) + (L & 15);
        const short* qb  = qhp + ((size_t)(b << 11) + row) * HD_;
        const short* qbl = qlp + ((size_t)(b << 11) + row) * HD_;
        #pragma unroll
        for (int dc = 0; dc < 2; ++dc) {
            int off = dc * 32 + (L >> 4) * 8;
            qfh[rt][dc] = *(const bf16x8*)(qb + off);
            qfl[rt][dc] = *(const bf16x8*)(qbl + off);
        }
    }
    // stats
    float ms[2][4], is[2][4];
    int rowg[2][4];
    #pragma unroll
    for (int rt = 0; rt < 2; ++rt)
        #pragma unroll
        for (int r = 0; r < 4; ++r) {
            int rg = (rt ? IB : IA) + (L >> 4) * 4 + r;
            rowg[rt][r] = rg;
            ms[rt][r] = msp[(b << 11) + rg];
            is[rt][r] = ilp[(b << 11) + rg];
        }

    const int nA = (IA + 143) >> 7;
    const int nB = (IB + 143) >> 7;
    const int rtp = wv & 1, dh = (wv >> 1) & 1, khf = wv >> 2;
    f32x4 ov[2];
    ov[0] = {0.f, 0.f, 0.f, 0.f};
    ov[1] = {0.f, 0.f, 0.f, 0.f};
    float dn[2][4];
    #pragma unroll
    for (int rt = 0; rt < 2; ++rt)
        #pragma unroll
        for (int r = 0; r < 4; ++r) dn[rt][r] = 0.f;

    for (int jt = 0; jt < nB; ++jt) {
        __syncthreads();                           // es reuse guard
        // ---- S phase: wave strip = cols wv*16..+16
        const int colL = wv * 16 + (L & 15);
        const int gcol = (b << 11) + jt * 128 + colL;
        const short* kb  = khp + (size_t)gcol * HD_ + (L >> 4) * 8;
        const short* kb2 = klp + (size_t)gcol * HD_ + (L >> 4) * 8;
        bf16x8 kf0 = *(const bf16x8*)kb;
        bf16x8 kf1 = *(const bf16x8*)(kb + 32);
        bf16x8 kl0 = *(const bf16x8*)kb2;
        bf16x8 kl1 = *(const bf16x8*)(kb2 + 32);
        for (int rt = 0; rt < 2; ++rt) {
            if (rt == 0 && jt >= nA) continue;     // block-uniform
            f32x4 s = {0.f, 0.f, 0.f, 0.f};
            s = MFMA_BF16(qfl[rt][0], kf0, s);
            s = MFMA_BF16(qfh[rt][0], kl0, s);
            s = MFMA_BF16(qfh[rt][0], kf0, s);
            s = MFMA_BF16(qfl[rt][1], kf1, s);
            s = MFMA_BF16(qfh[rt][1], kl1, s);
            s = MFMA_BF16(qfh[rt][1], kf1, s);
            const int colg = jt * 128 + colL;
            #pragma unroll
            for (int r = 0; r < 4; ++r) {
                float pv = __expf(s[r] - ms[rt][r]) * is[rt][r];
                float ev = (colg <= rowg[rt][r]) ? __expf(pv) : 0.f;
                dn[rt][r] += ev;
                int rid = rt * 16 + (L >> 4) * 4 + r;
                es[rid * 132 + colL] = ev;
            }
        }
        __syncthreads();                           // es ready
        // ---- PV phase: wave = (rtp, dh, khf)
        if (!(rtp == 0 && jt >= nA)) {
            #pragma unroll
            for (int u = 0; u < 2; ++u) {
                const int kc = khf * 2 + u;
                const int rid = rtp * 16 + (L & 15);
                const float* ep = &es[rid * 132 + kc * 32 + (L >> 4) * 8];
                float4 e0 = *(const float4*)ep;
                float4 e1 = *(const float4*)(ep + 4);
                bf16x8 ef;
                ef[0] = f2bf(e0.x); ef[1] = f2bf(e0.y);
                ef[2] = f2bf(e0.z); ef[3] = f2bf(e0.w);
                ef[4] = f2bf(e1.x); ef[5] = f2bf(e1.y);
                ef[6] = f2bf(e1.z); ef[7] = f2bf(e1.w);
                #pragma unroll
                for (int dt = 0; dt < 2; ++dt) {
                    int d = dh * 32 + dt * 16 + (L & 15);
                    const short* vp = vtp + ((size_t)(b * 64 + d) << 11)
                                    + jt * 128 + kc * 32 + (L >> 4) * 8;
                    bf16x8 vf = *(const bf16x8*)vp;
                    ov[dt] = MFMA_BF16(ef, vf, ov[dt]);
                }
            }
        }
    }

    // ---- den reduce
    #pragma unroll
    for (int off = 1; off < 16; off <<= 1)
        #pragma unroll
        for (int rt = 0; rt < 2; ++rt)
            #pragma unroll
            for (int r = 0; r < 4; ++r)
                dn[rt][r] += __shfl_xor(dn[rt][r], off, 64);
    if ((L & 15) == 0) {
        #pragma unroll
        for (int rt = 0; rt < 2; ++rt)
            #pragma unroll
            for (int r = 0; r < 4; ++r) {
                int rid = rt * 16 + (L >> 4) * 4 + r;
                red[wv * 32 + rid] = dn[rt][r];
            }
    }
    __syncthreads();
    if (t < 32) {
        float D = 0.f;
        #pragma unroll
        for (int w = 0; w < 8; ++w) D += red[w * 32 + t];
        dinv[t] = 1.f / D;
    }
    __syncthreads();
    if (khf == 1) {
        #pragma unroll
        for (int dt = 0; dt < 2; ++dt)
            #pragma unroll
            for (int r = 0; r < 4; ++r)
                obuf[((wv - 4) * 64 + L) * 8 + dt * 4 + r] = ov[dt][r];
    }
    __syncthreads();
    if (khf == 0) {
        float* ob = out + (size_t)(b << 11) * HD_;
        #pragma unroll
        for (int dt = 0; dt < 2; ++dt)
            #pragma unroll
            for (int r = 0; r < 4; ++r) {
                float o = ov[dt][r] + obuf[(wv * 64 + L) * 8 + dt * 4 + r];
                int rid = rtp * 16 + (L >> 4) * 4 + r;
                int row = (rtp ? IB : IA) + (L >> 4) * 4 + r;
                int d = dh * 32 + dt * 16 + (L & 15);
                ob[(size_t)row * HD_ + d] = o * dinv[rid];
            }
    }
}

// ---------------------------------------------------------------------------
extern "C" void kernel_launch(void* const* d_in, const int* in_sizes, int n_in,
                              void* d_out, int out_size, void* d_ws, size_t ws_size,
                              hipStream_t stream) {
    (void)in_sizes; (void)n_in; (void)out_size; (void)ws_size;
    const float* x  = (const float*)d_in[0];
    const float* Wq = (const float*)d_in[1];
    const float* Wk = (const float*)d_in[2];
    const float* Wv = (const float*)d_in[3];
    float* outp = (float*)d_out;

    char* ws = (char*)d_ws;                       // 5.75 MB used (proven size)
    short* wt  = (short*)ws;                      // 768 KB (dead after proj)
    float* msp = (float*)ws;                      // 32 KB (overlays wt, post-proj)
    float* ilp = (float*)(ws + 32768);            // 32 KB
    short* qh = (short*)(ws + 786432);
    short* ql = (short*)(ws + 786432 + 1048576);
    short* kh = (short*)(ws + 786432 + 2 * 1048576);
    short* kl = (short*)(ws + 786432 + 3 * 1048576);
    short* vt = (short*)(ws + 786432 + 4 * 1048576);  // [4][64][2048] bf16

    prep_w_kernel<<<dim3(16, 3), 256, 0, stream>>>(Wq, Wk, Wv, wt);
    qkv_proj_kernel<<<dim3(256), 512, 0, stream>>>(x, wt, qh, ql, kh, kl, vt);
    stats_kernel<<<dim3(512), 256, 0, stream>>>(qh, ql, kh, kl, msp, ilp);
    pv_kernel<<<dim3(256), 512, 0, stream>>>(qh, ql, kh, kl, vt, msp, ilp, outp);
}

// Round 7
// 179.876 us; speedup vs baseline: 1.0212x; 1.0212x over previous
//
#include <hip/hip_runtime.h>
#include <math.h>

#define T_  2048
#define C_  1024
#define HD_ 64

typedef __attribute__((ext_vector_type(8))) short bf16x8;   // 8 bf16 = 4 VGPRs
typedef __attribute__((ext_vector_type(4))) float f32x4;    // MFMA C/D

#define MFMA_BF16(A, B, C) __builtin_amdgcn_mfma_f32_16x16x32_bf16(A, B, C, 0, 0, 0)

// Intra-wave LDS ordering fence: compiler memory barrier + drain of all
// outstanding DS ops. Makes a same-wave ds_write -> ds_read (cross-lane)
// round-trip well-defined without a block barrier.
#define WAVE_LDS_FENCE() do {                                   \
    __builtin_amdgcn_wave_barrier();                            \
    __asm__ volatile("s_waitcnt lgkmcnt(0)" ::: "memory");      \
    __builtin_amdgcn_wave_barrier();                            \
} while (0)

__device__ __forceinline__ short f2bf(float f) {
    union { float f; unsigned u; } v; v.f = f;
    unsigned r = v.u + 0x7fffu + ((v.u >> 16) & 1u);   // RTNE
    return (short)(r >> 16);
}
__device__ __forceinline__ float bf2f(short s) {
    union { float f; unsigned u; } v;
    v.u = ((unsigned)(unsigned short)s) << 16;
    return v.f;
}

// ---------------------------------------------------------------------------
// K0: W[1024][64] fp32 -> wt[m][pl][64 h][1024 c] bf16 hi/lo (transposed).
// ---------------------------------------------------------------------------
__global__ __launch_bounds__(256) void prep_w_kernel(
    const float* __restrict__ Wq, const float* __restrict__ Wk,
    const float* __restrict__ Wv, short* __restrict__ wt)
{
    __shared__ __align__(16) short hi_l[64 * 72], lo_l[64 * 72];
    const int m = blockIdx.y;
    const float* W = (m == 0) ? Wq : (m == 1) ? Wk : Wv;
    const int t = threadIdx.x;
    const int C0 = blockIdx.x * 64;
    {
        const int c = t >> 2, hq = t & 3;
        const float4* wp = (const float4*)(W + (size_t)(C0 + c) * HD_ + hq * 16);
        #pragma unroll
        for (int u = 0; u < 4; ++u) {
            float4 f = wp[u];
            float vs[4] = {f.x, f.y, f.z, f.w};
            #pragma unroll
            for (int e = 0; e < 4; ++e) {
                int h = hq * 16 + u * 4 + e;
                short hh = f2bf(vs[e]);
                hi_l[h * 72 + c] = hh;
                lo_l[h * 72 + c] = f2bf(vs[e] - bf2f(hh));
            }
        }
    }
    __syncthreads();
    {
        const int h = t >> 2, cc = (t & 3) * 16;
        short* dh = wt + (size_t)(m * 2 + 0) * 65536 + h * 1024 + C0 + cc;
        short* dl = wt + (size_t)(m * 2 + 1) * 65536 + h * 1024 + C0 + cc;
        *(bf16x8*)dh       = *(const bf16x8*)&hi_l[h * 72 + cc];
        *(bf16x8*)(dh + 8) = *(const bf16x8*)&hi_l[h * 72 + cc + 8];
        *(bf16x8*)dl       = *(const bf16x8*)&lo_l[h * 72 + cc];
        *(bf16x8*)(dl + 8) = *(const bf16x8*)&lo_l[h * 72 + cc + 8];
    }
}

// ---------------------------------------------------------------------------
// K1: QKV projection, fully wave-autonomous (ZERO barriers, zero LDS).
// grid 256 x 512 thr. Block = 32 rows; wave = (rt = 16-row half, colq =
// 16-h quarter). Each wave: q,k triple hi/lo MFMA + v single-plane swapped
// (-> vT), FULL C loop (32 iters x 32 k — R5/R6 bug was 16 iters = half C).
// ---------------------------------------------------------------------------
__global__ __launch_bounds__(512) void qkv_proj_kernel(
    const float* __restrict__ x, const short* __restrict__ wt,
    short* __restrict__ qhp, short* __restrict__ qlp,
    short* __restrict__ khp, short* __restrict__ klp,
    short* __restrict__ vtp)
{
    const int t = threadIdx.x, L = t & 63, wv = t >> 6;
    const int rt = wv & 1, colq = wv >> 1;
    const int R0 = blockIdx.x * 32 + rt * 16;
    const int h = colq * 16 + (L & 15);
    const int quad = L >> 4;

    f32x4 aq = {0.f, 0.f, 0.f, 0.f};
    f32x4 ak = {0.f, 0.f, 0.f, 0.f};
    f32x4 av = {0.f, 0.f, 0.f, 0.f};

    const float* xp  = x + (size_t)(R0 + (L & 15)) * C_ + quad * 8;
    const short* wqh = wt + (size_t)0 * 65536 + h * 1024 + quad * 8;
    const short* wql = wt + (size_t)1 * 65536 + h * 1024 + quad * 8;
    const short* wkh = wt + (size_t)2 * 65536 + h * 1024 + quad * 8;
    const short* wkl = wt + (size_t)3 * 65536 + h * 1024 + quad * 8;
    const short* wvh = wt + (size_t)4 * 65536 + h * 1024 + quad * 8;

    for (int it = 0; it < 32; ++it) {      // 32 x 32 = full C=1024
        const int c0 = it * 32;
        float4 f0 = *(const float4*)(xp + c0);
        float4 f1 = *(const float4*)(xp + c0 + 4);
        bf16x8 qh_f = *(const bf16x8*)(wqh + c0);
        bf16x8 ql_f = *(const bf16x8*)(wql + c0);
        bf16x8 kh_f = *(const bf16x8*)(wkh + c0);
        bf16x8 kl_f = *(const bf16x8*)(wkl + c0);
        bf16x8 vh_f = *(const bf16x8*)(wvh + c0);
        float vs[8] = {f0.x, f0.y, f0.z, f0.w, f1.x, f1.y, f1.z, f1.w};
        bf16x8 axh, axl;
        #pragma unroll
        for (int e = 0; e < 8; ++e) {
            short hh = f2bf(vs[e]);
            axh[e] = hh;
            axl[e] = f2bf(vs[e] - bf2f(hh));
        }
        aq = MFMA_BF16(axl, qh_f, aq);
        aq = MFMA_BF16(axh, ql_f, aq);
        aq = MFMA_BF16(axh, qh_f, aq);
        ak = MFMA_BF16(axl, kh_f, ak);
        ak = MFMA_BF16(axh, kl_f, ak);
        ak = MFMA_BF16(axh, kh_f, ak);
        av = MFMA_BF16(vh_f, axh, av);     // swapped -> D[h][t]
    }

    #pragma unroll
    for (int r = 0; r < 4; ++r) {
        int row = R0 + quad * 4 + r;
        float vq = aq[r] * 8.f;            // fold sqrt(HD)=8 into q
        short hq2 = f2bf(vq);
        qhp[(size_t)row * HD_ + h] = hq2;
        qlp[(size_t)row * HD_ + h] = f2bf(vq - bf2f(hq2));
        float vk = ak[r];
        short hk2 = f2bf(vk);
        khp[(size_t)row * HD_ + h] = hk2;
        klp[(size_t)row * HD_ + h] = f2bf(vk - bf2f(hk2));
        int d = colq * 16 + quad * 4 + r;
        int tt = R0 + (L & 15);
        int bb = tt >> 11, tl = tt & (T_ - 1);
        vtp[(size_t)(bb * 64 + d) * T_ + tl] = f2bf(av[r]);
    }
}

// ---------------------------------------------------------------------------
// K2: full-row softmax stats. grid 256 x 512 thr. Block = 32 rows; wave =
// 256-col segment (16 col-tiles, independent chains). Zero loop barriers.
// ---------------------------------------------------------------------------
__global__ __launch_bounds__(512) void stats_kernel(
    const short* __restrict__ qhp, const short* __restrict__ qlp,
    const short* __restrict__ khp, const short* __restrict__ klp,
    float* __restrict__ msp, float* __restrict__ ilp)
{
    __shared__ float statb[8][32][2];

    const int t = threadIdx.x, L = t & 63, wv = t >> 6;
    const int quad = L >> 4;
    const int R0 = blockIdx.x * 32;           // global row tile
    const int b = R0 >> 11;

    bf16x8 qfh[2][2], qfl[2][2];
    #pragma unroll
    for (int rt = 0; rt < 2; ++rt) {
        int row = R0 + rt * 16 + (L & 15);
        #pragma unroll
        for (int dc = 0; dc < 2; ++dc) {
            size_t off = (size_t)row * HD_ + dc * 32 + quad * 8;
            qfh[rt][dc] = *(const bf16x8*)(qhp + off);
            qfl[rt][dc] = *(const bf16x8*)(qlp + off);
        }
    }

    float M[2][4], S[2][4];
    #pragma unroll
    for (int rt = 0; rt < 2; ++rt)
        #pragma unroll
        for (int r = 0; r < 4; ++r) { M[rt][r] = -3e38f; S[rt][r] = 0.f; }

    #pragma unroll 4
    for (int ct = 0; ct < 16; ++ct) {
        int gcol = (b << 11) + wv * 256 + ct * 16 + (L & 15);
        const short* kb  = khp + (size_t)gcol * HD_ + quad * 8;
        const short* kb2 = klp + (size_t)gcol * HD_ + quad * 8;
        bf16x8 kf0 = *(const bf16x8*)kb;
        bf16x8 kf1 = *(const bf16x8*)(kb + 32);
        bf16x8 kl0 = *(const bf16x8*)kb2;
        bf16x8 kl1 = *(const bf16x8*)(kb2 + 32);
        #pragma unroll
        for (int rt = 0; rt < 2; ++rt) {
            f32x4 s = {0.f, 0.f, 0.f, 0.f};
            s = MFMA_BF16(qfl[rt][0], kf0, s);
            s = MFMA_BF16(qfh[rt][0], kl0, s);
            s = MFMA_BF16(qfh[rt][0], kf0, s);
            s = MFMA_BF16(qfl[rt][1], kf1, s);
            s = MFMA_BF16(qfh[rt][1], kl1, s);
            s = MFMA_BF16(qfh[rt][1], kf1, s);
            #pragma unroll
            for (int r = 0; r < 4; ++r) {
                float mn = fmaxf(M[rt][r], s[r]);
                S[rt][r] = S[rt][r] * __expf(M[rt][r] - mn) + __expf(s[r] - mn);
                M[rt][r] = mn;
            }
        }
    }
    #pragma unroll
    for (int off = 1; off < 16; off <<= 1)
        #pragma unroll
        for (int rt = 0; rt < 2; ++rt)
            #pragma unroll
            for (int r = 0; r < 4; ++r) {
                float mo = __shfl_xor(M[rt][r], off, 64);
                float lo = __shfl_xor(S[rt][r], off, 64);
                float mn = fmaxf(M[rt][r], mo);
                S[rt][r] = S[rt][r] * __expf(M[rt][r] - mn) + lo * __expf(mo - mn);
                M[rt][r] = mn;
            }
    if ((L & 15) == 0) {
        #pragma unroll
        for (int rt = 0; rt < 2; ++rt)
            #pragma unroll
            for (int r = 0; r < 4; ++r) {
                int rid = rt * 16 + quad * 4 + r;
                statb[wv][rid][0] = M[rt][r];
                statb[wv][rid][1] = S[rt][r];
            }
    }
    __syncthreads();
    if (t < 32) {
        float Mm = statb[0][t][0], Ss = statb[0][t][1];
        #pragma unroll
        for (int w = 1; w < 8; ++w) {
            float mo = statb[w][t][0], lo = statb[w][t][1];
            float mn = fmaxf(Mm, mo);
            Ss = Ss * __expf(Mm - mn) + lo * __expf(mo - mn);
            Mm = mn;
        }
        msp[R0 + t] = Mm;
        ilp[R0 + t] = 1.f / Ss;
    }
}

// ---------------------------------------------------------------------------
// K3: causal second softmax + PV, wave-autonomous k-loop (no block barriers
// in the loop). grid 512 x 512 thr, balanced pairing across CU rounds.
// Wave w owns k-tiles jt = w, w+8, ... ; C->A layout transform through a
// wave-PRIVATE LDS slab, ordered by WAVE_LDS_FENCE. 2 block barriers total.
// ---------------------------------------------------------------------------
__global__ __launch_bounds__(512, 2) void pv_kernel(
    const short* __restrict__ qhp, const short* __restrict__ qlp,
    const short* __restrict__ khp, const short* __restrict__ klp,
    const short* __restrict__ vtp, const float* __restrict__ msp,
    const float* __restrict__ ilp, float* __restrict__ out)
{
    __shared__ __align__(16) float es32[8][16][36];  // 18.4 KB, per-wave slabs
    __shared__ float obuf[8][16][68];                // 34.8 KB
    __shared__ float denb[8][16];
    __shared__ float dinv[16];

    const int t = threadIdx.x, L = t & 63, wv = t >> 6;
    const int quad = L >> 4;
    const int g = blockIdx.x;
    const int slot = g & 255, rnd = g >> 8;
    const int b = slot & 3, j = slot >> 2;
    const int p = rnd ? (127 - j) : j;       // CU gets j+1 + 128-j tiles: balanced
    const int IA = p * 16;
    const int nT = (p >> 3) + 1;             // causal 128-col tiles

    // q fragments (A-layout: lane holds row IA+(L&15), k = quad*8..)
    bf16x8 qfh[2], qfl[2];
    {
        size_t base = ((size_t)(b << 11) + IA + (L & 15)) * HD_;
        #pragma unroll
        for (int dc = 0; dc < 2; ++dc) {
            qfh[dc] = *(const bf16x8*)(qhp + base + dc * 32 + quad * 8);
            qfl[dc] = *(const bf16x8*)(qlp + base + dc * 32 + quad * 8);
        }
    }
    // row stats for this lane's C-layout rows (quad*4+r)
    float ms[4], il[4];
    #pragma unroll
    for (int r = 0; r < 4; ++r) {
        int gr = (b << 11) + IA + quad * 4 + r;
        ms[r] = msp[gr];
        il[r] = ilp[gr];
    }

    f32x4 ov[4];
    #pragma unroll
    for (int dt = 0; dt < 4; ++dt) ov[dt] = {0.f, 0.f, 0.f, 0.f};
    float den[4] = {0.f, 0.f, 0.f, 0.f};
    float* myes = &es32[wv][0][0];

    for (int jt = wv; jt < nT; jt += 8) {
        #pragma unroll
        for (int ch = 0; ch < 4; ++ch) {
            #pragma unroll
            for (int cg2 = 0; cg2 < 2; ++cg2) {
                const int colL = ch * 32 + cg2 * 16 + (L & 15);
                const int gcol = (b << 11) + jt * 128 + colL;
                const short* kb  = khp + (size_t)gcol * HD_ + quad * 8;
                const short* kb2 = klp + (size_t)gcol * HD_ + quad * 8;
                bf16x8 kf0 = *(const bf16x8*)kb;
                bf16x8 kf1 = *(const bf16x8*)(kb + 32);
                bf16x8 kl0 = *(const bf16x8*)kb2;
                bf16x8 kl1 = *(const bf16x8*)(kb2 + 32);
                f32x4 s = {0.f, 0.f, 0.f, 0.f};
                s = MFMA_BF16(qfl[0], kf0, s);
                s = MFMA_BF16(qfh[0], kl0, s);
                s = MFMA_BF16(qfh[0], kf0, s);
                s = MFMA_BF16(qfl[1], kf1, s);
                s = MFMA_BF16(qfh[1], kl1, s);
                s = MFMA_BF16(qfh[1], kf1, s);
                const int colg = jt * 128 + colL;
                #pragma unroll
                for (int r = 0; r < 4; ++r) {
                    float pvv = __expf(s[r] - ms[r]) * il[r];
                    float ev = (colg <= IA + quad * 4 + r) ? __expf(pvv) : 0.f;
                    den[r] += ev;
                    myes[(quad * 4 + r) * 36 + cg2 * 16 + (L & 15)] = ev;
                }
            }
            // ---- intra-wave C->A transform, fenced
            WAVE_LDS_FENCE();
            const float* ep = &myes[(L & 15) * 36 + quad * 8];
            float4 e0 = *(const float4*)ep;
            float4 e1 = *(const float4*)(ep + 4);
            WAVE_LDS_FENCE();   // reads done before next chunk overwrites
            bf16x8 ef;
            ef[0] = f2bf(e0.x); ef[1] = f2bf(e0.y);
            ef[2] = f2bf(e0.z); ef[3] = f2bf(e0.w);
            ef[4] = f2bf(e1.x); ef[5] = f2bf(e1.y);
            ef[6] = f2bf(e1.z); ef[7] = f2bf(e1.w);
            #pragma unroll
            for (int dt = 0; dt < 4; ++dt) {
                const int d = dt * 16 + (L & 15);
                const short* vp = vtp + ((size_t)(b * 64 + d) << 11)
                                + jt * 128 + ch * 32 + quad * 8;
                bf16x8 vf = *(const bf16x8*)vp;
                ov[dt] = MFMA_BF16(ef, vf, ov[dt]);
            }
        }
    }

    // den: reduce over the 16 col-lanes of each quad
    #pragma unroll
    for (int off = 1; off < 16; off <<= 1)
        #pragma unroll
        for (int r = 0; r < 4; ++r)
            den[r] += __shfl_xor(den[r], off, 64);
    if ((L & 15) == 0) {
        #pragma unroll
        for (int r = 0; r < 4; ++r)
            denb[wv][quad * 4 + r] = den[r];
    }
    // stage O partials
    #pragma unroll
    for (int dt = 0; dt < 4; ++dt)
        #pragma unroll
        for (int r = 0; r < 4; ++r)
            obuf[wv][quad * 4 + r][dt * 16 + (L & 15)] = ov[dt][r];
    __syncthreads();
    if (t < 16) {
        float D = 0.f;
        #pragma unroll
        for (int w = 0; w < 8; ++w) D += denb[w][t];
        dinv[t] = 1.f / D;
    }
    __syncthreads();
    // output: 16 rows x 64 d = 1024 elems, 512 threads x 2
    #pragma unroll
    for (int u = 0; u < 2; ++u) {
        int idx = t + u * 512;
        int row = idx >> 6, d = idx & 63;
        float o = 0.f;
        #pragma unroll
        for (int w = 0; w < 8; ++w) o += obuf[w][row][d];
        out[((size_t)(b << 11) + IA + row) * HD_ + d] = o * dinv[row];
    }
}

// ---------------------------------------------------------------------------
extern "C" void kernel_launch(void* const* d_in, const int* in_sizes, int n_in,
                              void* d_out, int out_size, void* d_ws, size_t ws_size,
                              hipStream_t stream) {
    (void)in_sizes; (void)n_in; (void)out_size; (void)ws_size;
    const float* x  = (const float*)d_in[0];
    const float* Wq = (const float*)d_in[1];
    const float* Wk = (const float*)d_in[2];
    const float* Wv = (const float*)d_in[3];
    float* outp = (float*)d_out;

    char* ws = (char*)d_ws;                       // 5.75 MB used (proven size)
    short* wt  = (short*)ws;                      // 768 KB (dead after proj)
    float* msp = (float*)ws;                      // 32 KB (overlays wt post-proj)
    float* ilp = (float*)(ws + 32768);            // 32 KB
    short* qh = (short*)(ws + 786432);
    short* ql = (short*)(ws + 786432 + 1048576);
    short* kh = (short*)(ws + 786432 + 2 * 1048576);
    short* kl = (short*)(ws + 786432 + 3 * 1048576);
    short* vt = (short*)(ws + 786432 + 4 * 1048576);  // [4][64][2048] bf16

    prep_w_kernel<<<dim3(16, 3), 256, 0, stream>>>(Wq, Wk, Wv, wt);
    qkv_proj_kernel<<<dim3(256), 512, 0, stream>>>(x, wt, qh, ql, kh, kl, vt);
    stats_kernel<<<dim3(256), 512, 0, stream>>>(qh, ql, kh, kl, msp, ilp);
    pv_kernel<<<dim3(512), 512, 0, stream>>>(qh, ql, kh, kl, vt, msp, ilp, outp);
}